// Round 14
// baseline (280.789 us; speedup 1.0000x reference)
//
#include <hip/hip_runtime.h>
#include <hip/hip_bf16.h>
#include <math.h>

#define B_ 8
#define S_ 1024
#define D_ 768
#define H_ 12
// DH = 64
#define QSCALE 0.18033688011112042f  // 0.125 * log2(e): softmax done base-2

typedef __attribute__((ext_vector_type(8))) short short8;
typedef __attribute__((ext_vector_type(4))) float floatx4;
typedef unsigned short ushort_t;

__device__ __forceinline__ ushort_t f2bf(float f) {  // RNE fp32 -> bf16
  unsigned int u = __builtin_bit_cast(unsigned int, f);
  u += 0x7fffu + ((u >> 16) & 1u);
  return (ushort_t)(u >> 16);
}

__device__ __forceinline__ unsigned int pkbf(float a, float b) {
  // packed RNE fp32x2 -> bf16x2 (v_cvt_pk_bf16_f32 on gfx950)
  __hip_bfloat162 h = __float22bfloat162_rn(make_float2(a, b));
  unsigned int r;
  __builtin_memcpy(&r, &h, sizeof(r));  // bit_cast rejects non-trivial type
  return r;
}

// Branch-free GELU (exact erf formulation, A&S 7.1.26, |eps_erf|<=1.5e-7).
__device__ __forceinline__ float gelu_f(float x) {
  const float z = fabsf(x) * 0.70710678118654752f;
  const float t = __builtin_amdgcn_rcpf(1.0f + 0.3275911f * z);
  const float p =
      t * (0.254829592f +
           t * (-0.284496736f +
                t * (1.421413741f + t * (-1.453152027f + t * 1.061405429f))));
  const float e = __expf(-z * z);
  const float erfv = 1.0f - p * e;  // erf(|x|/sqrt2)
  return 0.5f * x * (1.0f + copysignf(erfv, x));
}

template <int N>
__device__ __forceinline__ void wait_vmcnt() {
  if constexpr (N == 0)
    asm volatile("s_waitcnt vmcnt(0)" ::: "memory");
  else if constexpr (N == 3)
    asm volatile("s_waitcnt vmcnt(3)" ::: "memory");
  else if constexpr (N == 4)
    asm volatile("s_waitcnt vmcnt(4)" ::: "memory");
  else if constexpr (N == 6)
    asm volatile("s_waitcnt vmcnt(6)" ::: "memory");
  else
    asm volatile("s_waitcnt vmcnt(8)" ::: "memory");
}

// ------------- LayerNorm: one wave per row, shfl-only reduction -----------
__global__ __launch_bounds__(256) void ln_bf16(
    const float* __restrict__ in, const float* __restrict__ g,
    const float* __restrict__ bias, ushort_t* __restrict__ out) {
  const int row = blockIdx.x * 4 + (threadIdx.x >> 6);
  const int lane = threadIdx.x & 63;
  const float* p = in + (size_t)row * D_;
  float4 v[3];
#pragma unroll
  for (int j = 0; j < 3; ++j) v[j] = *(const float4*)(p + j * 256 + lane * 4);
  float s = 0.f;
#pragma unroll
  for (int j = 0; j < 3; ++j) s += (v[j].x + v[j].y) + (v[j].z + v[j].w);
#pragma unroll
  for (int m = 1; m < 64; m <<= 1) s += __shfl_xor(s, m);
  const float mean = s * (1.0f / D_);
  float q = 0.f;
#pragma unroll
  for (int j = 0; j < 3; ++j) {
    const float a = v[j].x - mean, b = v[j].y - mean;
    const float c = v[j].z - mean, d = v[j].w - mean;
    q += (a * a + b * b) + (c * c + d * d);
  }
#pragma unroll
  for (int m = 1; m < 64; m <<= 1) q += __shfl_xor(q, m);
  const float rstd = rsqrtf(q * (1.0f / D_) + 1e-5f);
  ushort_t* o = out + (size_t)row * D_;
#pragma unroll
  for (int j = 0; j < 3; ++j) {
    const float4 gv = *(const float4*)(g + j * 256 + lane * 4);
    const float4 bv = *(const float4*)(bias + j * 256 + lane * 4);
    const unsigned int p01 = pkbf((v[j].x - mean) * rstd * gv.x + bv.x,
                                  (v[j].y - mean) * rstd * gv.y + bv.y);
    const unsigned int p23 = pkbf((v[j].z - mean) * rstd * gv.z + bv.z,
                                  (v[j].w - mean) * rstd * gv.w + bv.w);
    *(uint2*)(o + j * 256 + lane * 4) = make_uint2(p01, p23);
  }
}

// --------- fused weight prep: W1^T, W2^T (32x32 tiles) + per-head 64x64 ----
__device__ __forceinline__ void tcast_body(
    const float* __restrict__ W, ushort_t* __restrict__ Wt,
    int Kdim, int Ndim, int bx, int by, float* sh) {
  float(*tile)[33] = (float(*)[33])sh;
  const int n0 = bx * 32, k0 = by * 32;
  const int tx = threadIdx.x & 31, ty = threadIdx.x >> 5;  // ty 0..7
#pragma unroll
  for (int i = 0; i < 32; i += 8)
    tile[ty + i][tx] = W[(size_t)(k0 + ty + i) * Ndim + n0 + tx];
  __syncthreads();
#pragma unroll
  for (int i = 0; i < 32; i += 8)
    Wt[(size_t)(n0 + ty + i) * Kdim + k0 + tx] = f2bf(tile[tx][ty + i]);
}

__global__ __launch_bounds__(256) void prep_weights(
    const float* __restrict__ W1, ushort_t* __restrict__ Wt1,
    const float* __restrict__ W2, ushort_t* __restrict__ Wt2,
    const float* __restrict__ Wq, const float* __restrict__ Wk,
    const float* __restrict__ Wv, ushort_t* __restrict__ Wqt,
    ushort_t* __restrict__ Wkt, ushort_t* __restrict__ Wvt) {
  __shared__ float sh[64 * 65];
  const int bid = blockIdx.x;
  if (bid < 2304) {  // W1: K=768(24 tiles) x N=3072(96 tiles)
    tcast_body(W1, Wt1, 768, 3072, bid % 96, bid / 96, sh);
  } else if (bid < 4608) {  // W2: K=3072(96) x N=768(24)
    const int idx = bid - 2304;
    tcast_body(W2, Wt2, 3072, 768, idx % 24, idx / 24, sh);
  } else {  // 36 blocks: per-head 64x64 transpose of Wq/Wk/Wv
    const int idx = bid - 4608;
    const int h = idx % 12, which = idx / 12;
    const float* W = which == 0 ? Wq : which == 1 ? Wk : Wv;
    ushort_t* O = which == 0 ? Wqt : which == 1 ? Wkt : Wvt;
    float(*t)[65] = (float(*)[65])sh;
    const int tid = threadIdx.x;
#pragma unroll
    for (int i = 0; i < 16; ++i) {
      const int idx2 = tid + i * 256;
      t[idx2 >> 6][idx2 & 63] = W[h * 4096 + idx2];
    }
    __syncthreads();
#pragma unroll
    for (int i = 0; i < 16; ++i) {
      const int idx2 = tid + i * 256;
      O[h * 4096 + idx2] = f2bf(t[idx2 & 63][idx2 >> 6]);  // O[e][d]=W[d][e]
    }
  }
}

// -------- QKV projection, bf16 MFMA; coalesced stores via wave-private LDS -
// (r7 structure, measured-good)
__global__ __launch_bounds__(256) void qkv_mfma(
    const ushort_t* __restrict__ xbf,
    const ushort_t* __restrict__ Wqt, const ushort_t* __restrict__ Wkt,
    const ushort_t* __restrict__ Wvt,
    const float* __restrict__ bq, const float* __restrict__ bk,
    const float* __restrict__ bv,
    ushort_t* __restrict__ qo, ushort_t* __restrict__ ko,
    ushort_t* __restrict__ vt) {
  const int h = blockIdx.y;
  const int mb = blockIdx.x * 128;
  const int tid = threadIdx.x;
  const int wave = tid >> 6, lane = tid & 63;
  const int lc = lane & 15, kq = lane >> 4;
  const int wm = wave * 32;

  __shared__ __align__(16) ushort_t Lb[4][2560];
  ushort_t* Lw = Lb[wave];

  short8 af[2][2];
#pragma unroll
  for (int mi = 0; mi < 2; ++mi)
#pragma unroll
    for (int kc = 0; kc < 2; ++kc)
      af[mi][kc] = *(const short8*)(xbf + (size_t)(mb + wm + mi * 16 + lc) * D_ +
                                    h * 64 + kc * 32 + kq * 8);

  const ushort_t* Wp[3] = {Wqt + h * 4096, Wkt + h * 4096, Wvt + h * 4096};
  floatx4 accT[2][2][4] = {};  // Q,K swapped: [w3][mi][n], lane: s=mi*16+lc
  floatx4 accV[2][4] = {};     // V: [mi][n], lane: e=n*16+lc
#pragma unroll
  for (int n = 0; n < 4; ++n)
#pragma unroll
    for (int kc = 0; kc < 2; ++kc) {
      const short8 wq_ = *(const short8*)(Wp[0] + (n * 16 + lc) * 64 +
                                          kc * 32 + kq * 8);
      const short8 wk_ = *(const short8*)(Wp[1] + (n * 16 + lc) * 64 +
                                          kc * 32 + kq * 8);
      const short8 wv_ = *(const short8*)(Wp[2] + (n * 16 + lc) * 64 +
                                          kc * 32 + kq * 8);
#pragma unroll
      for (int mi = 0; mi < 2; ++mi) {
        accT[0][mi][n] = __builtin_amdgcn_mfma_f32_16x16x32_bf16(
            wq_, af[mi][kc], accT[0][mi][n], 0, 0, 0);
        accT[1][mi][n] = __builtin_amdgcn_mfma_f32_16x16x32_bf16(
            wk_, af[mi][kc], accT[1][mi][n], 0, 0, 0);
        accV[mi][n] = __builtin_amdgcn_mfma_f32_16x16x32_bf16(
            af[mi][kc], wv_, accV[mi][n], 0, 0, 0);
      }
    }

  const int b = mb >> 10;
  const size_t obase = (size_t)(b * H_ + h) * (S_ * 64);
  const int sbase = (mb & 1023) + wm;

#pragma unroll
  for (int w3 = 0; w3 < 2; ++w3) {
    const float* bias = (w3 == 0 ? bq : bk) + h * 64;
    ushort_t* outp = w3 == 0 ? qo : ko;
#pragma unroll
    for (int mi = 0; mi < 2; ++mi)
#pragma unroll
      for (int n = 0; n < 4; ++n) {
        const float4 bv4 = *(const float4*)(bias + n * 16 + kq * 4);
        const floatx4 v = accT[w3][mi][n];
        float v0 = v[0] + bv4.x, v1 = v[1] + bv4.y;
        float v2 = v[2] + bv4.z, v3 = v[3] + bv4.w;
        if (w3 == 0) { v0 *= QSCALE; v1 *= QSCALE; v2 *= QSCALE; v3 *= QSCALE; }
        *(uint2*)(&Lw[(mi * 16 + lc) * 72 + n * 16 + kq * 4]) =
            make_uint2(pkbf(v0, v1), pkbf(v2, v3));
      }
    asm volatile("s_waitcnt lgkmcnt(0)" ::: "memory");
    const int srow = lane >> 2, c16 = (lane & 3) * 16;
#pragma unroll
    for (int it = 0; it < 2; ++it) {
      const int s = it * 16 + srow;
      const uint4 r0 = *(const uint4*)(&Lw[s * 72 + c16]);
      const uint4 r1 = *(const uint4*)(&Lw[s * 72 + c16 + 8]);
      *(uint4*)(outp + obase + (size_t)(sbase + s) * 64 + c16) = r0;
      *(uint4*)(outp + obase + (size_t)(sbase + s) * 64 + c16 + 8) = r1;
    }
    asm volatile("s_waitcnt lgkmcnt(0)" ::: "memory");  // reads done, reuse Lw
  }

#pragma unroll
  for (int n = 0; n < 4; ++n) {
    const float bvv = bv[h * 64 + n * 16 + lc];
#pragma unroll
    for (int mi = 0; mi < 2; ++mi) {
      const floatx4 v = accV[mi][n];
      *(uint2*)(&Lw[(n * 16 + lc) * 40 + mi * 16 + kq * 4]) =
          make_uint2(pkbf(v[0] + bvv, v[1] + bvv),
                     pkbf(v[2] + bvv, v[3] + bvv));
    }
  }
  asm volatile("s_waitcnt lgkmcnt(0)" ::: "memory");
  {
    const int erow = lane >> 2, s8 = (lane & 3) * 8;
#pragma unroll
    for (int it = 0; it < 4; ++it) {
      const int e = it * 16 + erow;
      const uint4 r0 = *(const uint4*)(&Lw[e * 40 + s8]);
      *(uint4*)(vt + obase + (size_t)e * S_ + sbase + s8) = r0;
    }
  }
}

// ------- flash attention: 8 waves x 16 q, K/V LDS-staged + XOR-swizzled ----
// (r9 structure — the version in the best-measured round)
__global__ __launch_bounds__(512) void attn_mfma(
    const ushort_t* __restrict__ qb, const ushort_t* __restrict__ kb,
    const ushort_t* __restrict__ vt, const float* __restrict__ x,
    float* __restrict__ out1) {
  const int bh = blockIdx.x;
  const int tid = threadIdx.x;
  const int wave = tid >> 6, lane = tid & 63;  // wave 0..7
  const int lc = lane & 15, kq = lane >> 4;
  const int q0 = blockIdx.y * 128 + wave * 16;

  __shared__ __align__(16) ushort_t smem[8192 + 8 * 16 * 72];  // 34816 B
  ushort_t* Ks = smem;                       // [key][d], chunk-swizzled
  ushort_t* Vs = smem + 4096;                // [d][s],  chunk-swizzled
  ushort_t* Pp = smem + 8192 + wave * (16 * 72);

  const ushort_t* qp = qb + (size_t)bh * (S_ * 64);
  const ushort_t* kp = kb + (size_t)bh * (S_ * 64);
  const ushort_t* vp = vt + (size_t)bh * (S_ * 64);

  short8 qf[2];
#pragma unroll
  for (int kc = 0; kc < 2; ++kc)
    qf[kc] = *(const short8*)(qp + (size_t)(q0 + lc) * 64 + kc * 32 + kq * 8);

  const int srow = tid >> 3;                             // 0..63
  const int sgc = ((tid & 7) ^ (srow & 7)) * 8;          // global col (elems)
  const int slds = srow * 64 + (tid & 7) * 8;            // LDS offset (elems)
  const int swz = lc & 7;                                // frag-read swizzle

  float l_r = 0.0f;
  floatx4 oacc[4] = {};  // [d-tile]

  for (int kt = 0; kt < 16; ++kt) {
    __builtin_amdgcn_global_load_lds(
        (const __attribute__((address_space(1))) unsigned int*)
            (kp + (size_t)(kt * 64 + srow) * 64 + sgc),
        (__attribute__((address_space(3))) unsigned int*)(Ks + slds), 16, 0, 0);
    __builtin_amdgcn_global_load_lds(
        (const __attribute__((address_space(1))) unsigned int*)
            (vp + (size_t)srow * S_ + kt * 64 + sgc),
        (__attribute__((address_space(3))) unsigned int*)(Vs + slds), 16, 0, 0);
    __syncthreads();

    floatx4 sacc[4] = {};
#pragma unroll
    for (int mi = 0; mi < 4; ++mi) {
      const int row = (mi * 16 + lc) * 64;
#pragma unroll
      for (int kc = 0; kc < 2; ++kc) {
        const short8 kf =
            *(const short8*)(Ks + row + ((kc * 4 + kq) ^ swz) * 8);
        sacc[mi] = __builtin_amdgcn_mfma_f32_16x16x32_bf16(
            kf, qf[kc], sacc[mi], 0, 0, 0);
      }
    }

    float pr[4][4];
    float sm = 0.f;
#pragma unroll
    for (int mi = 0; mi < 4; ++mi)
#pragma unroll
      for (int r = 0; r < 4; ++r) {
        pr[mi][r] = exp2f(sacc[mi][r]);
        sm += pr[mi][r];
      }
    l_r += sm;  // per-lane partial; reduced at epilogue
#pragma unroll
    for (int mi = 0; mi < 4; ++mi) {
      const unsigned int p01 = pkbf(pr[mi][0], pr[mi][1]);
      const unsigned int p23 = pkbf(pr[mi][2], pr[mi][3]);
      *(uint2*)(&Pp[lc * 72 + mi * 16 + kq * 4]) = make_uint2(p01, p23);
    }
    asm volatile("s_waitcnt lgkmcnt(0)" ::: "memory");

    short8 pf[2];
#pragma unroll
    for (int kc = 0; kc < 2; ++kc)
      pf[kc] = *(const short8*)(&Pp[lc * 72 + kc * 32 + kq * 8]);
#pragma unroll
    for (int mi = 0; mi < 4; ++mi) {
      const int row = (mi * 16 + lc) * 64;
#pragma unroll
      for (int kc = 0; kc < 2; ++kc) {
        const short8 vf =
            *(const short8*)(Vs + row + ((kc * 4 + kq) ^ swz) * 8);
        oacc[mi] = __builtin_amdgcn_mfma_f32_16x16x32_bf16(
            vf, pf[kc], oacc[mi], 0, 0, 0);
      }
    }
    __syncthreads();  // Ks/Vs/Pp reads done before next stage overwrites
  }

  const int b = bh / H_, h = bh % H_;
  float lt = l_r;
  lt += __shfl_xor(lt, 16);
  lt += __shfl_xor(lt, 32);
  const float inv = 1.0f / lt;
  float* Ow = (float*)smem + wave * 1088;
#pragma unroll
  for (int mi = 0; mi < 4; ++mi) {
    floatx4 ov = oacc[mi];
    ov[0] *= inv; ov[1] *= inv; ov[2] *= inv; ov[3] *= inv;
    *(floatx4*)(&Ow[lc * 68 + mi * 16 + kq * 4]) = ov;
  }
  asm volatile("s_waitcnt lgkmcnt(0)" ::: "memory");
  const int row = (lane >> 3) & 7, c8 = (lane & 7) * 4;
#pragma unroll
  for (int rg = 0; rg < 2; ++rg) {
    const int qq = rg * 8 + row;
    const size_t gbase =
        ((size_t)(b * S_) + q0 + qq) * D_ + h * 64 + c8;
#pragma unroll
    for (int j = 0; j < 2; ++j) {
      const float4 ov = *(const float4*)(&Ow[qq * 68 + j * 32 + c8]);
      const float4 xv = *(const float4*)(x + gbase + j * 32);
      *(float4*)(out1 + gbase + j * 32) =
          make_float4(ov.x + xv.x, ov.y + xv.y, ov.z + xv.z, ov.w + xv.w);
    }
  }
}

// ===== phase-interleaved GEMM, m201 ORDERING: 128x256, 3 buffers ==========
// r13->r14 change vs r11's gemm_8ph: phase ordering becomes
//   reads-issue -> stage-issue -> S_BARRIER -> lgkmcnt(0) -> MFMA -> S_BARRIER
// (barrier BEFORE the lgkm wait: each wave's ds_read latency drains while it
// waits at the barrier for the other waves' issue, so the lgkm wait is ~free;
// the double barrier phase-locks waves into LDS-quiet/LDS-busy alternation —
// the m201 pattern).  Pure ADDED synchronization vs r11 (verified correct):
// no new race surface; acc order (t asc, ks asc) unchanged -> bit-identical.
// vmcnt(6) once per K-tile at p3 (tile t+1 resident, t+2's 6 in flight).
// XCD col-major rectangle map (r13-validated): 8 xcd x (8 mb x 12 nb),
// concurrent set 8 A-panels + B-panels ~3.1 MB < 4 MB per-XCD L2.
template <int N, int K, bool GELU, bool OUT_BF16>
__global__ __launch_bounds__(512, 2) void gemm_8ph(
    const ushort_t* __restrict__ A, const ushort_t* __restrict__ Bt,
    void* __restrict__ Cout) {
  constexpr int BM = 128, BN = 256;
  constexpr int NT = K / 64;
  constexpr int TSZ = (BM + BN) * 64;  // 24576 ush = 48 KB per buffer

  const int lin = blockIdx.x;                 // 768 blocks
  const int xcd = lin & 7, slot = lin >> 3;   // slot 0..95
  const int mbg = slot & 7, nbi = slot >> 3;  // col-major 8 rows x 12 cols
  const int mb = (xcd * 8 + mbg) * BM;
  const int nb = nbi * BN;

  const int tid = threadIdx.x;
  const int wave = tid >> 6, lane = tid & 63;
  const int wm = (wave >> 2) * 64;   // 2 M-groups
  const int wn = (wave & 3) * 64;    // 4 N-groups

  __shared__ __align__(16) ushort_t Ls[3][TSZ];  // 144 KB

  const int sr = tid >> 3;                      // 0..63
  const int sc8 = (tid & 7) * 8;                // LDS chunk (lane-linear dest)
  const int sgx = ((tid & 7) ^ (sr & 7)) * 8;   // pre-swizzled global chunk

  auto stageA = [&](int t, int buf) {
    const int kb = t * 64;
#pragma unroll
    for (int j = 0; j < 2; ++j) {
      const int row = j * 64 + sr;
      __builtin_amdgcn_global_load_lds(
          (const __attribute__((address_space(1))) unsigned int*)
              (A + (size_t)(mb + row) * K + kb + sgx),
          (__attribute__((address_space(3))) unsigned int*)
              (&Ls[buf][row * 64 + sc8]), 16, 0, 0);
    }
  };
  auto stageB = [&](int t, int buf, int half) {
    const int kb = t * 64;
#pragma unroll
    for (int j = 0; j < 2; ++j) {
      const int row = half * 128 + j * 64 + sr;
      __builtin_amdgcn_global_load_lds(
          (const __attribute__((address_space(1))) unsigned int*)
              (Bt + (size_t)(nb + row) * K + kb + sgx),
          (__attribute__((address_space(3))) unsigned int*)
              (&Ls[buf][BM * 64 + row * 64 + sc8]), 16, 0, 0);
    }
  };

  // prologue: tiles 0,1 fully issued (12 loads); wait tile 0 (6 remain)
  stageA(0, 0); stageB(0, 0, 0); stageB(0, 0, 1);
  stageA(1, 1); stageB(1, 1, 0); stageB(1, 1, 1);
  wait_vmcnt<6>();
  __builtin_amdgcn_s_barrier();
  __builtin_amdgcn_sched_barrier(0);

  const int lc = lane & 15, kq = lane >> 4, swz = lc & 7;
  floatx4 acc[4][4] = {};

#pragma unroll 1
  for (int t = 0; t < NT; ++t) {
    const int buf = t % 3;
    const int nbuf = (t + 2) % 3;
    const bool pre = (t + 2 < NT);
    const ushort_t* As = &Ls[buf][0];
    const ushort_t* Bs = &Ls[buf][BM * 64];
    short8 af[4][2], bfr[4][2];

    // ---- phase 0: issue af01+bfr01 + stageA(t+2) | BAR | lgkm | q(0,0) ----
#pragma unroll
    for (int i = 0; i < 2; ++i)
#pragma unroll
      for (int ks = 0; ks < 2; ++ks) {
        af[i][ks] = *(const short8*)(As + (wm + i * 16 + lc) * 64 +
                                     ((ks * 4 + kq) ^ swz) * 8);
        bfr[i][ks] = *(const short8*)(Bs + (wn + i * 16 + lc) * 64 +
                                      ((ks * 4 + kq) ^ swz) * 8);
      }
    if (pre) stageA(t + 2, nbuf);
    __builtin_amdgcn_sched_barrier(0);
    __builtin_amdgcn_s_barrier();  // waves arrive with reads in flight
    asm volatile("s_waitcnt lgkmcnt(0)" ::: "memory");
    __builtin_amdgcn_sched_barrier(0);
    __builtin_amdgcn_s_setprio(1);
#pragma unroll
    for (int i = 0; i < 2; ++i)
#pragma unroll
      for (int j = 0; j < 2; ++j) {
        acc[i][j] = __builtin_amdgcn_mfma_f32_16x16x32_bf16(
            af[i][0], bfr[j][0], acc[i][j], 0, 0, 0);
        acc[i][j] = __builtin_amdgcn_mfma_f32_16x16x32_bf16(
            af[i][1], bfr[j][1], acc[i][j], 0, 0, 0);
      }
    __builtin_amdgcn_s_setprio(0);
    __builtin_amdgcn_sched_barrier(0);
    __builtin_amdgcn_s_barrier();
    __builtin_amdgcn_sched_barrier(0);

    // ---- phase 1: issue bfr23 + stageB0(t+2) | BAR | lgkm | q(0,1) ----
#pragma unroll
    for (int j = 2; j < 4; ++j)
#pragma unroll
      for (int ks = 0; ks < 2; ++ks)
        bfr[j][ks] = *(const short8*)(Bs + (wn + j * 16 + lc) * 64 +
                                      ((ks * 4 + kq) ^ swz) * 8);
    if (pre) stageB(t + 2, nbuf, 0);
    __builtin_amdgcn_sched_barrier(0);
    __builtin_amdgcn_s_barrier();
    asm volatile("s_waitcnt lgkmcnt(0)" ::: "memory");
    __builtin_amdgcn_sched_barrier(0);
    __builtin_amdgcn_s_setprio(1);
#pragma unroll
    for (int i = 0; i < 2; ++i)
#pragma unroll
      for (int j = 2; j < 4; ++j) {
        acc[i][j] = __builtin_amdgcn_mfma_f32_16x16x32_bf16(
            af[i][0], bfr[j][0], acc[i][j], 0, 0, 0);
        acc[i][j] = __builtin_amdgcn_mfma_f32_16x16x32_bf16(
            af[i][1], bfr[j][1], acc[i][j], 0, 0, 0);
      }
    __builtin_amdgcn_s_setprio(0);
    __builtin_amdgcn_sched_barrier(0);
    __builtin_amdgcn_s_barrier();
    __builtin_amdgcn_sched_barrier(0);

    // ---- phase 2: issue af23 + stageB1(t+2) | BAR | lgkm | q(1,0) ----
#pragma unroll
    for (int i = 2; i < 4; ++i)
#pragma unroll
      for (int ks = 0; ks < 2; ++ks)
        af[i][ks] = *(const short8*)(As + (wm + i * 16 + lc) * 64 +
                                     ((ks * 4 + kq) ^ swz) * 8);
    if (pre) stageB(t + 2, nbuf, 1);
    __builtin_amdgcn_sched_barrier(0);
    __builtin_amdgcn_s_barrier();
    asm volatile("s_waitcnt lgkmcnt(0)" ::: "memory");
    __builtin_amdgcn_sched_barrier(0);
    __builtin_amdgcn_s_setprio(1);
#pragma unroll
    for (int i = 2; i < 4; ++i)
#pragma unroll
      for (int j = 0; j < 2; ++j) {
        acc[i][j] = __builtin_amdgcn_mfma_f32_16x16x32_bf16(
            af[i][0], bfr[j][0], acc[i][j], 0, 0, 0);
        acc[i][j] = __builtin_amdgcn_mfma_f32_16x16x32_bf16(
            af[i][1], bfr[j][1], acc[i][j], 0, 0, 0);
      }
    __builtin_amdgcn_s_setprio(0);
    __builtin_amdgcn_sched_barrier(0);
    __builtin_amdgcn_s_barrier();
    __builtin_amdgcn_sched_barrier(0);

    // ---- phase 3: q(1,1) (register-only) | counted vmcnt | BAR ----
    __builtin_amdgcn_s_setprio(1);
#pragma unroll
    for (int i = 2; i < 4; ++i)
#pragma unroll
      for (int j = 2; j < 4; ++j) {
        acc[i][j] = __builtin_amdgcn_mfma_f32_16x16x32_bf16(
            af[i][0], bfr[j][0], acc[i][j], 0, 0, 0);
        acc[i][j] = __builtin_amdgcn_mfma_f32_16x16x32_bf16(
            af[i][1], bfr[j][1], acc[i][j], 0, 0, 0);
      }
    __builtin_amdgcn_s_setprio(0);
    if (t + 1 < NT) {
      if (pre)
        wait_vmcnt<6>();  // tile t+1 landed; t+2's 6 loads stay in flight
      else
        wait_vmcnt<0>();  // tail
      __builtin_amdgcn_s_barrier();
      __builtin_amdgcn_sched_barrier(0);
    }
  }

  const int lcol = lane & 15, lr4 = (lane >> 4) * 4;
#pragma unroll
  for (int i = 0; i < 4; ++i)
#pragma unroll
    for (int r = 0; r < 4; ++r) {
      const int m = mb + wm + i * 16 + lr4 + r;
#pragma unroll
      for (int j = 0; j < 4; ++j) {
        const int col = nb + wn + j * 16 + lcol;
        float vv = acc[i][j][r];
        if (GELU) vv = gelu_f(vv);
        if (OUT_BF16)
          ((ushort_t*)Cout)[(size_t)m * N + col] = f2bf(vv);
        else
          ((float*)Cout)[(size_t)m * N + col] = vv;
      }
    }
}

// ======== pipelined bf16 MFMA GEMM (r9 structure, for GEMM2) ========
template <int BM, int BN, int N, int K, bool GELU, bool RESID, bool OUT_BF16,
          int XCDMODE>
__global__ __launch_bounds__(512, 4) void gemm_pipe(
    const ushort_t* __restrict__ A, const ushort_t* __restrict__ Bt,
    const float* __restrict__ resid, void* __restrict__ Cout) {
  constexpr int MI = BM / 32;             // m-frags per wave
  constexpr int NJ = BN / 64;             // n-frags per wave
  constexpr int LPT = BM / 64 + BN / 64;  // gload_lds per thread per K-tile
  constexpr int NT = K / 64;

  int mb, nb;
  if constexpr (XCDMODE == 1) {
    const int lin = blockIdx.x;
    const int xcd = lin & 7, slot = lin >> 3;
    const int mbg = slot / (N / 128), nbi = slot - mbg * (N / 128);
    mb = (xcd * 16 + mbg) * 64;
    nb = nbi * 128;
  } else {
    nb = blockIdx.x * BN;
    mb = blockIdx.y * BM;
  }

  const int tid = threadIdx.x;
  const int wave = tid >> 6, lane = tid & 63;  // wave 0..7
  const int wm = (wave >> 2) * (BM / 2), wn = (wave & 3) * (BN / 4);

  __shared__ __align__(16) ushort_t Asp[2][BM * 64];
  __shared__ __align__(16) ushort_t Bsp[2][BN * 64];

  const int sr = tid >> 3;                      // 0..63
  const int sc8 = (tid & 7) * 8;                // LDS chunk (lane-linear dest)
  const int sgx = ((tid & 7) ^ (sr & 7)) * 8;   // pre-swizzled global chunk

  auto stage = [&](int t, int buf) {
    const int kb = t * 64;
#pragma unroll
    for (int j = 0; j < BM / 64; ++j) {
      const int row = j * 64 + sr;
      __builtin_amdgcn_global_load_lds(
          (const __attribute__((address_space(1))) unsigned int*)
              (A + (size_t)(mb + row) * K + kb + sgx),
          (__attribute__((address_space(3))) unsigned int*)
              (&Asp[buf][row * 64 + sc8]), 16, 0, 0);
    }
#pragma unroll
    for (int j = 0; j < BN / 64; ++j) {
      const int row = j * 64 + sr;
      __builtin_amdgcn_global_load_lds(
          (const __attribute__((address_space(1))) unsigned int*)
              (Bt + (size_t)(nb + row) * K + kb + sgx),
          (__attribute__((address_space(3))) unsigned int*)
              (&Bsp[buf][row * 64 + sc8]), 16, 0, 0);
    }
  };

  stage(0, 0);
  stage(1, 1);
  wait_vmcnt<LPT>();
  __builtin_amdgcn_s_barrier();
  __builtin_amdgcn_sched_barrier(0);

  const int lc = lane & 15, kq = lane >> 4, swz = lc & 7;
  floatx4 acc[MI][NJ] = {};

#pragma unroll 1
  for (int t = 0; t < NT; ++t) {
    const int cur = t & 1;
    short8 af[MI][2], bfr[NJ][2];
#pragma unroll
    for (int ks = 0; ks < 2; ++ks) {
#pragma unroll
      for (int i = 0; i < MI; ++i)
        af[i][ks] = *(const short8*)(&Asp[cur][(wm + i * 16 + lc) * 64 +
                                               ((ks * 4 + kq) ^ swz) * 8]);
#pragma unroll
      for (int j = 0; j < NJ; ++j)
        bfr[j][ks] = *(const short8*)(&Bsp[cur][(wn + j * 16 + lc) * 64 +
                                                ((ks * 4 + kq) ^ swz) * 8]);
    }
    __builtin_amdgcn_s_setprio(1);
#pragma unroll
    for (int i = 0; i < MI; ++i)
#pragma unroll
      for (int j = 0; j < NJ; ++j)
        acc[i][j] = __builtin_amdgcn_mfma_f32_16x16x32_bf16(
            af[i][0], bfr[j][0], acc[i][j], 0, 0, 0);
    __builtin_amdgcn_s_setprio(0);
    asm volatile("s_waitcnt lgkmcnt(0)" ::: "memory");
    __builtin_amdgcn_sched_barrier(0);
    __builtin_amdgcn_s_barrier();  // #1: all waves' frag reads complete
    __builtin_amdgcn_sched_barrier(0);
    if (t + 2 < NT) stage(t + 2, cur);  // overwrite just-freed buffer
    __builtin_amdgcn_sched_barrier(0);
    if (t + 2 < NT)
      wait_vmcnt<LPT>();
    else if (t + 1 < NT)
      wait_vmcnt<0>();
    if (t + 1 < NT) {
      __builtin_amdgcn_s_barrier();  // #2: tile t+1 resident on every wave
      __builtin_amdgcn_sched_barrier(0);
    }
    __builtin_amdgcn_s_setprio(1);
#pragma unroll
    for (int i = 0; i < MI; ++i)
#pragma unroll
      for (int j = 0; j < NJ; ++j)
        acc[i][j] = __builtin_amdgcn_mfma_f32_16x16x32_bf16(
            af[i][1], bfr[j][1], acc[i][j], 0, 0, 0);
    __builtin_amdgcn_s_setprio(0);
  }

  const int lcol = lane & 15, lr4 = (lane >> 4) * 4;
#pragma unroll
  for (int i = 0; i < MI; ++i)
#pragma unroll
    for (int r = 0; r < 4; ++r) {
      const int m = mb + wm + i * 16 + lr4 + r;
#pragma unroll
      for (int j = 0; j < NJ; ++j) {
        const int col = nb + wn + j * 16 + lcol;
        float vv = acc[i][j][r];
        if (GELU) vv = gelu_f(vv);
        if (RESID) vv += resid[(size_t)m * N + col];
        if (OUT_BF16)
          ((ushort_t*)Cout)[(size_t)m * N + col] = f2bf(vv);
        else
          ((float*)Cout)[(size_t)m * N + col] = vv;
      }
    }
}

extern "C" void kernel_launch(void* const* d_in, const int* in_sizes, int n_in,
                              void* d_out, int out_size, void* d_ws, size_t ws_size,
                              hipStream_t stream) {
  (void)in_sizes; (void)n_in; (void)out_size; (void)ws_size;
  const float* x     = (const float*)d_in[0];
  const float* ln1_g = (const float*)d_in[1];
  const float* ln1_b = (const float*)d_in[2];
  const float* Wq    = (const float*)d_in[3];
  const float* bq    = (const float*)d_in[4];
  const float* Wk    = (const float*)d_in[5];
  const float* bk    = (const float*)d_in[6];
  const float* Wv    = (const float*)d_in[7];
  const float* bv    = (const float*)d_in[8];
  const float* ln2_g = (const float*)d_in[9];
  const float* ln2_b = (const float*)d_in[10];
  const float* W1    = (const float*)d_in[11];
  const float* W2    = (const float*)d_in[12];
  float* out = (float*)d_out;

  const size_t n = (size_t)B_ * S_ * D_;  // 6,291,456
  ushort_t* u = (ushort_t*)d_ws;
  ushort_t* xbf  = u;                 // LN1 out bf16
  ushort_t* qb   = xbf + n;           // [96][1024][64]
  ushort_t* kb   = qb + n;
  ushort_t* vt   = kb + n;            // [96][64][1024]  (written by qkv)
  ushort_t* xbf2 = vt + n;            // LN2 out bf16
  ushort_t* act  = xbf2 + n;          // 8192 x 3072
  ushort_t* Wt1  = act + (size_t)8192 * 3072;
  ushort_t* Wt2  = Wt1 + (size_t)3072 * 768;
  ushort_t* Wqt  = Wt2 + (size_t)768 * 3072;
  ushort_t* Wkt  = Wqt + H_ * 4096;
  ushort_t* Wvt  = Wkt + H_ * 4096;
  float* out1 = (float*)(Wvt + H_ * 4096);  // x + attn (fp32), n floats

  prep_weights<<<dim3(4644), dim3(256), 0, stream>>>(
      W1, Wt1, W2, Wt2, Wq, Wk, Wv, Wqt, Wkt, Wvt);
  ln_bf16<<<dim3(2048), dim3(256), 0, stream>>>(x, ln1_g, ln1_b, xbf);
  qkv_mfma<<<dim3(64, 12), dim3(256), 0, stream>>>(xbf, Wqt, Wkt, Wvt,
                                                   bq, bk, bv, qb, kb, vt);
  attn_mfma<<<dim3(96, 8), dim3(512), 0, stream>>>(qb, kb, vt, x, out1);
  ln_bf16<<<dim3(2048), dim3(256), 0, stream>>>(out1, ln2_g, ln2_b, xbf2);
  // FFN GEMM1: 8192x3072x768, GELU, bf16 out
  // (128x256, 3 buffers, m201 phase ordering, XCD rectangle map, 768 blks)
  gemm_8ph<3072, 768, true, true>
      <<<dim3(768), dim3(512), 0, stream>>>(xbf2, Wt1, act);
  // FFN GEMM2: 8192x768x3072, +resid, fp32 out (64x128, 8 waves, XCD map 1)
  gemm_pipe<64, 128, 768, 3072, false, true, false, 1>
      <<<dim3(768), dim3(512), 0, stream>>>(act, Wt2, out1, out);
}

// Round 15
// 278.881 us; speedup vs baseline: 1.0068x; 1.0068x over previous
//
#include <hip/hip_runtime.h>
#include <hip/hip_bf16.h>
#include <math.h>

#define B_ 8
#define S_ 1024
#define D_ 768
#define H_ 12
// DH = 64
#define QSCALE 0.18033688011112042f  // 0.125 * log2(e): softmax done base-2

typedef __attribute__((ext_vector_type(8))) short short8;
typedef __attribute__((ext_vector_type(4))) float floatx4;
typedef unsigned short ushort_t;

__device__ __forceinline__ ushort_t f2bf(float f) {  // RNE fp32 -> bf16
  unsigned int u = __builtin_bit_cast(unsigned int, f);
  u += 0x7fffu + ((u >> 16) & 1u);
  return (ushort_t)(u >> 16);
}

__device__ __forceinline__ unsigned int pkbf(float a, float b) {
  // packed RNE fp32x2 -> bf16x2 (v_cvt_pk_bf16_f32 on gfx950)
  __hip_bfloat162 h = __float22bfloat162_rn(make_float2(a, b));
  unsigned int r;
  __builtin_memcpy(&r, &h, sizeof(r));  // bit_cast rejects non-trivial type
  return r;
}

// Branch-free GELU (exact erf formulation, A&S 7.1.26, |eps_erf|<=1.5e-7).
__device__ __forceinline__ float gelu_f(float x) {
  const float z = fabsf(x) * 0.70710678118654752f;
  const float t = __builtin_amdgcn_rcpf(1.0f + 0.3275911f * z);
  const float p =
      t * (0.254829592f +
           t * (-0.284496736f +
                t * (1.421413741f + t * (-1.453152027f + t * 1.061405429f))));
  const float e = __expf(-z * z);
  const float erfv = 1.0f - p * e;  // erf(|x|/sqrt2)
  return 0.5f * x * (1.0f + copysignf(erfv, x));
}

template <int N>
__device__ __forceinline__ void wait_vmcnt() {
  if constexpr (N == 0)
    asm volatile("s_waitcnt vmcnt(0)" ::: "memory");
  else if constexpr (N == 3)
    asm volatile("s_waitcnt vmcnt(3)" ::: "memory");
  else if constexpr (N == 4)
    asm volatile("s_waitcnt vmcnt(4)" ::: "memory");
  else if constexpr (N == 6)
    asm volatile("s_waitcnt vmcnt(6)" ::: "memory");
  else
    asm volatile("s_waitcnt vmcnt(8)" ::: "memory");
}

// ---------------- LayerNorm body: one wave per row, shfl reduction --------
__device__ __forceinline__ void ln_body(
    const float* __restrict__ in, const float* __restrict__ g,
    const float* __restrict__ bias, ushort_t* __restrict__ out, int row) {
  const int lane = threadIdx.x & 63;
  const float* p = in + (size_t)row * D_;
  float4 v[3];
#pragma unroll
  for (int j = 0; j < 3; ++j) v[j] = *(const float4*)(p + j * 256 + lane * 4);
  float s = 0.f;
#pragma unroll
  for (int j = 0; j < 3; ++j) s += (v[j].x + v[j].y) + (v[j].z + v[j].w);
#pragma unroll
  for (int m = 1; m < 64; m <<= 1) s += __shfl_xor(s, m);
  const float mean = s * (1.0f / D_);
  float q = 0.f;
#pragma unroll
  for (int j = 0; j < 3; ++j) {
    const float a = v[j].x - mean, b = v[j].y - mean;
    const float c = v[j].z - mean, d = v[j].w - mean;
    q += (a * a + b * b) + (c * c + d * d);
  }
#pragma unroll
  for (int m = 1; m < 64; m <<= 1) q += __shfl_xor(q, m);
  const float rstd = rsqrtf(q * (1.0f / D_) + 1e-5f);
  ushort_t* o = out + (size_t)row * D_;
#pragma unroll
  for (int j = 0; j < 3; ++j) {
    const float4 gv = *(const float4*)(g + j * 256 + lane * 4);
    const float4 bv = *(const float4*)(bias + j * 256 + lane * 4);
    const unsigned int p01 = pkbf((v[j].x - mean) * rstd * gv.x + bv.x,
                                  (v[j].y - mean) * rstd * gv.y + bv.y);
    const unsigned int p23 = pkbf((v[j].z - mean) * rstd * gv.z + bv.z,
                                  (v[j].w - mean) * rstd * gv.w + bv.w);
    *(uint2*)(o + j * 256 + lane * 4) = make_uint2(p01, p23);
  }
}

__global__ __launch_bounds__(256) void ln_bf16(
    const float* __restrict__ in, const float* __restrict__ g,
    const float* __restrict__ bias, ushort_t* __restrict__ out) {
  ln_body(in, g, bias, out, blockIdx.x * 4 + (threadIdx.x >> 6));
}

// --- fused prep: W1^T, W2^T, per-head QKV transpose, AND LN1 (independent) -
// Blocks 0..2303: W1 tiles; 2304..4607: W2 tiles; 4608..4643: Wq/Wk/Wv;
// 4644..6691: LN1 rows.  One launch instead of two serialized ones; the
// independent LN1 work overlaps the weight transposes.
__device__ __forceinline__ void tcast_body(
    const float* __restrict__ W, ushort_t* __restrict__ Wt,
    int Kdim, int Ndim, int bx, int by, float* sh) {
  float(*tile)[33] = (float(*)[33])sh;
  const int n0 = bx * 32, k0 = by * 32;
  const int tx = threadIdx.x & 31, ty = threadIdx.x >> 5;  // ty 0..7
#pragma unroll
  for (int i = 0; i < 32; i += 8)
    tile[ty + i][tx] = W[(size_t)(k0 + ty + i) * Ndim + n0 + tx];
  __syncthreads();
#pragma unroll
  for (int i = 0; i < 32; i += 8)
    Wt[(size_t)(n0 + ty + i) * Kdim + k0 + tx] = f2bf(tile[tx][ty + i]);
}

__global__ __launch_bounds__(256) void prep_ln(
    const float* __restrict__ W1, ushort_t* __restrict__ Wt1,
    const float* __restrict__ W2, ushort_t* __restrict__ Wt2,
    const float* __restrict__ Wq, const float* __restrict__ Wk,
    const float* __restrict__ Wv, ushort_t* __restrict__ Wqt,
    ushort_t* __restrict__ Wkt, ushort_t* __restrict__ Wvt,
    const float* __restrict__ x, const float* __restrict__ ln1_g,
    const float* __restrict__ ln1_b, ushort_t* __restrict__ xbf) {
  __shared__ float sh[64 * 65];
  const int bid = blockIdx.x;
  if (bid < 2304) {  // W1: K=768(24 tiles) x N=3072(96 tiles)
    tcast_body(W1, Wt1, 768, 3072, bid % 96, bid / 96, sh);
  } else if (bid < 4608) {  // W2: K=3072(96) x N=768(24)
    const int idx = bid - 2304;
    tcast_body(W2, Wt2, 3072, 768, idx % 24, idx / 24, sh);
  } else if (bid < 4644) {  // per-head 64x64 transpose of Wq/Wk/Wv
    const int idx = bid - 4608;
    const int h = idx % 12, which = idx / 12;
    const float* W = which == 0 ? Wq : which == 1 ? Wk : Wv;
    ushort_t* O = which == 0 ? Wqt : which == 1 ? Wkt : Wvt;
    float(*t)[65] = (float(*)[65])sh;
    const int tid = threadIdx.x;
#pragma unroll
    for (int i = 0; i < 16; ++i) {
      const int idx2 = tid + i * 256;
      t[idx2 >> 6][idx2 & 63] = W[h * 4096 + idx2];
    }
    __syncthreads();
#pragma unroll
    for (int i = 0; i < 16; ++i) {
      const int idx2 = tid + i * 256;
      O[h * 4096 + idx2] = f2bf(t[idx2 & 63][idx2 >> 6]);  // O[e][d]=W[d][e]
    }
  } else {  // LN1: 2048 blocks x 4 rows
    ln_body(x, ln1_g, ln1_b, xbf, (bid - 4644) * 4 + (threadIdx.x >> 6));
  }
}

// -------- QKV projection, bf16 MFMA; coalesced stores via wave-private LDS -
// (r7 structure, measured-good)
__global__ __launch_bounds__(256) void qkv_mfma(
    const ushort_t* __restrict__ xbf,
    const ushort_t* __restrict__ Wqt, const ushort_t* __restrict__ Wkt,
    const ushort_t* __restrict__ Wvt,
    const float* __restrict__ bq, const float* __restrict__ bk,
    const float* __restrict__ bv,
    ushort_t* __restrict__ qo, ushort_t* __restrict__ ko,
    ushort_t* __restrict__ vt) {
  const int h = blockIdx.y;
  const int mb = blockIdx.x * 128;
  const int tid = threadIdx.x;
  const int wave = tid >> 6, lane = tid & 63;
  const int lc = lane & 15, kq = lane >> 4;
  const int wm = wave * 32;

  __shared__ __align__(16) ushort_t Lb[4][2560];
  ushort_t* Lw = Lb[wave];

  short8 af[2][2];
#pragma unroll
  for (int mi = 0; mi < 2; ++mi)
#pragma unroll
    for (int kc = 0; kc < 2; ++kc)
      af[mi][kc] = *(const short8*)(xbf + (size_t)(mb + wm + mi * 16 + lc) * D_ +
                                    h * 64 + kc * 32 + kq * 8);

  const ushort_t* Wp[3] = {Wqt + h * 4096, Wkt + h * 4096, Wvt + h * 4096};
  floatx4 accT[2][2][4] = {};  // Q,K swapped: [w3][mi][n], lane: s=mi*16+lc
  floatx4 accV[2][4] = {};     // V: [mi][n], lane: e=n*16+lc
#pragma unroll
  for (int n = 0; n < 4; ++n)
#pragma unroll
    for (int kc = 0; kc < 2; ++kc) {
      const short8 wq_ = *(const short8*)(Wp[0] + (n * 16 + lc) * 64 +
                                          kc * 32 + kq * 8);
      const short8 wk_ = *(const short8*)(Wp[1] + (n * 16 + lc) * 64 +
                                          kc * 32 + kq * 8);
      const short8 wv_ = *(const short8*)(Wp[2] + (n * 16 + lc) * 64 +
                                          kc * 32 + kq * 8);
#pragma unroll
      for (int mi = 0; mi < 2; ++mi) {
        accT[0][mi][n] = __builtin_amdgcn_mfma_f32_16x16x32_bf16(
            wq_, af[mi][kc], accT[0][mi][n], 0, 0, 0);
        accT[1][mi][n] = __builtin_amdgcn_mfma_f32_16x16x32_bf16(
            wk_, af[mi][kc], accT[1][mi][n], 0, 0, 0);
        accV[mi][n] = __builtin_amdgcn_mfma_f32_16x16x32_bf16(
            af[mi][kc], wv_, accV[mi][n], 0, 0, 0);
      }
    }

  const int b = mb >> 10;
  const size_t obase = (size_t)(b * H_ + h) * (S_ * 64);
  const int sbase = (mb & 1023) + wm;

#pragma unroll
  for (int w3 = 0; w3 < 2; ++w3) {
    const float* bias = (w3 == 0 ? bq : bk) + h * 64;
    ushort_t* outp = w3 == 0 ? qo : ko;
#pragma unroll
    for (int mi = 0; mi < 2; ++mi)
#pragma unroll
      for (int n = 0; n < 4; ++n) {
        const float4 bv4 = *(const float4*)(bias + n * 16 + kq * 4);
        const floatx4 v = accT[w3][mi][n];
        float v0 = v[0] + bv4.x, v1 = v[1] + bv4.y;
        float v2 = v[2] + bv4.z, v3 = v[3] + bv4.w;
        if (w3 == 0) { v0 *= QSCALE; v1 *= QSCALE; v2 *= QSCALE; v3 *= QSCALE; }
        *(uint2*)(&Lw[(mi * 16 + lc) * 72 + n * 16 + kq * 4]) =
            make_uint2(pkbf(v0, v1), pkbf(v2, v3));
      }
    asm volatile("s_waitcnt lgkmcnt(0)" ::: "memory");
    const int srow = lane >> 2, c16 = (lane & 3) * 16;
#pragma unroll
    for (int it = 0; it < 2; ++it) {
      const int s = it * 16 + srow;
      const uint4 r0 = *(const uint4*)(&Lw[s * 72 + c16]);
      const uint4 r1 = *(const uint4*)(&Lw[s * 72 + c16 + 8]);
      *(uint4*)(outp + obase + (size_t)(sbase + s) * 64 + c16) = r0;
      *(uint4*)(outp + obase + (size_t)(sbase + s) * 64 + c16 + 8) = r1;
    }
    asm volatile("s_waitcnt lgkmcnt(0)" ::: "memory");  // reads done, reuse Lw
  }

#pragma unroll
  for (int n = 0; n < 4; ++n) {
    const float bvv = bv[h * 64 + n * 16 + lc];
#pragma unroll
    for (int mi = 0; mi < 2; ++mi) {
      const floatx4 v = accV[mi][n];
      *(uint2*)(&Lw[(n * 16 + lc) * 40 + mi * 16 + kq * 4]) =
          make_uint2(pkbf(v[0] + bvv, v[1] + bvv),
                     pkbf(v[2] + bvv, v[3] + bvv));
    }
  }
  asm volatile("s_waitcnt lgkmcnt(0)" ::: "memory");
  {
    const int erow = lane >> 2, s8 = (lane & 3) * 8;
#pragma unroll
    for (int it = 0; it < 4; ++it) {
      const int e = it * 16 + erow;
      const uint4 r0 = *(const uint4*)(&Lw[e * 40 + s8]);
      *(uint4*)(vt + obase + (size_t)e * S_ + sbase + s8) = r0;
    }
  }
}

// ------- flash attention: 8 waves x 16 q, K/V LDS-staged + XOR-swizzled ----
// (r9 structure — the version in the best-measured round)
__global__ __launch_bounds__(512) void attn_mfma(
    const ushort_t* __restrict__ qb, const ushort_t* __restrict__ kb,
    const ushort_t* __restrict__ vt, const float* __restrict__ x,
    float* __restrict__ out1) {
  const int bh = blockIdx.x;
  const int tid = threadIdx.x;
  const int wave = tid >> 6, lane = tid & 63;  // wave 0..7
  const int lc = lane & 15, kq = lane >> 4;
  const int q0 = blockIdx.y * 128 + wave * 16;

  __shared__ __align__(16) ushort_t smem[8192 + 8 * 16 * 72];  // 34816 B
  ushort_t* Ks = smem;                       // [key][d], chunk-swizzled
  ushort_t* Vs = smem + 4096;                // [d][s],  chunk-swizzled
  ushort_t* Pp = smem + 8192 + wave * (16 * 72);

  const ushort_t* qp = qb + (size_t)bh * (S_ * 64);
  const ushort_t* kp = kb + (size_t)bh * (S_ * 64);
  const ushort_t* vp = vt + (size_t)bh * (S_ * 64);

  short8 qf[2];
#pragma unroll
  for (int kc = 0; kc < 2; ++kc)
    qf[kc] = *(const short8*)(qp + (size_t)(q0 + lc) * 64 + kc * 32 + kq * 8);

  const int srow = tid >> 3;                             // 0..63
  const int sgc = ((tid & 7) ^ (srow & 7)) * 8;          // global col (elems)
  const int slds = srow * 64 + (tid & 7) * 8;            // LDS offset (elems)
  const int swz = lc & 7;                                // frag-read swizzle

  float l_r = 0.0f;
  floatx4 oacc[4] = {};  // [d-tile]

  for (int kt = 0; kt < 16; ++kt) {
    __builtin_amdgcn_global_load_lds(
        (const __attribute__((address_space(1))) unsigned int*)
            (kp + (size_t)(kt * 64 + srow) * 64 + sgc),
        (__attribute__((address_space(3))) unsigned int*)(Ks + slds), 16, 0, 0);
    __builtin_amdgcn_global_load_lds(
        (const __attribute__((address_space(1))) unsigned int*)
            (vp + (size_t)srow * S_ + kt * 64 + sgc),
        (__attribute__((address_space(3))) unsigned int*)(Vs + slds), 16, 0, 0);
    __syncthreads();

    floatx4 sacc[4] = {};
#pragma unroll
    for (int mi = 0; mi < 4; ++mi) {
      const int row = (mi * 16 + lc) * 64;
#pragma unroll
      for (int kc = 0; kc < 2; ++kc) {
        const short8 kf =
            *(const short8*)(Ks + row + ((kc * 4 + kq) ^ swz) * 8);
        sacc[mi] = __builtin_amdgcn_mfma_f32_16x16x32_bf16(
            kf, qf[kc], sacc[mi], 0, 0, 0);
      }
    }

    float pr[4][4];
    float sm = 0.f;
#pragma unroll
    for (int mi = 0; mi < 4; ++mi)
#pragma unroll
      for (int r = 0; r < 4; ++r) {
        pr[mi][r] = exp2f(sacc[mi][r]);
        sm += pr[mi][r];
      }
    l_r += sm;  // per-lane partial; reduced at epilogue
#pragma unroll
    for (int mi = 0; mi < 4; ++mi) {
      const unsigned int p01 = pkbf(pr[mi][0], pr[mi][1]);
      const unsigned int p23 = pkbf(pr[mi][2], pr[mi][3]);
      *(uint2*)(&Pp[lc * 72 + mi * 16 + kq * 4]) = make_uint2(p01, p23);
    }
    asm volatile("s_waitcnt lgkmcnt(0)" ::: "memory");

    short8 pf[2];
#pragma unroll
    for (int kc = 0; kc < 2; ++kc)
      pf[kc] = *(const short8*)(&Pp[lc * 72 + kc * 32 + kq * 8]);
#pragma unroll
    for (int mi = 0; mi < 4; ++mi) {
      const int row = (mi * 16 + lc) * 64;
#pragma unroll
      for (int kc = 0; kc < 2; ++kc) {
        const short8 vf =
            *(const short8*)(Vs + row + ((kc * 4 + kq) ^ swz) * 8);
        oacc[mi] = __builtin_amdgcn_mfma_f32_16x16x32_bf16(
            vf, pf[kc], oacc[mi], 0, 0, 0);
      }
    }
    __syncthreads();  // Ks/Vs/Pp reads done before next stage overwrites
  }

  const int b = bh / H_, h = bh % H_;
  float lt = l_r;
  lt += __shfl_xor(lt, 16);
  lt += __shfl_xor(lt, 32);
  const float inv = 1.0f / lt;
  float* Ow = (float*)smem + wave * 1088;
#pragma unroll
  for (int mi = 0; mi < 4; ++mi) {
    floatx4 ov = oacc[mi];
    ov[0] *= inv; ov[1] *= inv; ov[2] *= inv; ov[3] *= inv;
    *(floatx4*)(&Ow[lc * 68 + mi * 16 + kq * 4]) = ov;
  }
  asm volatile("s_waitcnt lgkmcnt(0)" ::: "memory");
  const int row = (lane >> 3) & 7, c8 = (lane & 7) * 4;
#pragma unroll
  for (int rg = 0; rg < 2; ++rg) {
    const int qq = rg * 8 + row;
    const size_t gbase =
        ((size_t)(b * S_) + q0 + qq) * D_ + h * 64 + c8;
#pragma unroll
    for (int j = 0; j < 2; ++j) {
      const float4 ov = *(const float4*)(&Ow[qq * 68 + j * 32 + c8]);
      const float4 xv = *(const float4*)(x + gbase + j * 32);
      *(float4*)(out1 + gbase + j * 32) =
          make_float4(ov.x + xv.x, ov.y + xv.y, ov.z + xv.z, ov.w + xv.w);
    }
  }
}

// ======== pipelined bf16 MFMA GEMM (r9 structure, measured-good) ========
// XCDMODE 1: GEMM2 map (xcd owns 16 mb-groups x all nb; proven N=768).
// XCDMODE 2: GEMM1 map (xcd owns 8 mb x 24 nb rectangle, slots col-major;
// concurrent set 8 A-panels + 8 B-panels = 3.2 MB < 4 MB per-XCD L2 —
// r13-measured: FETCH 57.6 -> 33.2 MB).
template <int BM, int BN, int N, int K, bool GELU, bool RESID, bool OUT_BF16,
          int XCDMODE>
__global__ __launch_bounds__(512, 4) void gemm_pipe(
    const ushort_t* __restrict__ A, const ushort_t* __restrict__ Bt,
    const float* __restrict__ resid, void* __restrict__ Cout) {
  constexpr int MI = BM / 32;             // m-frags per wave
  constexpr int NJ = BN / 64;             // n-frags per wave
  constexpr int LPT = BM / 64 + BN / 64;  // gload_lds per thread per K-tile
  constexpr int NT = K / 64;

  int mb, nb;
  if constexpr (XCDMODE == 1) {
    const int lin = blockIdx.x;
    const int xcd = lin & 7, slot = lin >> 3;
    const int mbg = slot / (N / 128), nbi = slot - mbg * (N / 128);
    mb = (xcd * 16 + mbg) * 64;
    nb = nbi * 128;
  } else if constexpr (XCDMODE == 2) {
    const int lin = blockIdx.x;          // 1536 blocks
    const int xcd = lin & 7, slot = lin >> 3;  // slot 0..191
    const int mbg = slot & 7, nbi = slot >> 3; // col-major: 8 rows x 24 cols
    mb = (xcd * 8 + mbg) * BM;
    nb = nbi * BN;
  } else {
    nb = blockIdx.x * BN;
    mb = blockIdx.y * BM;
  }

  const int tid = threadIdx.x;
  const int wave = tid >> 6, lane = tid & 63;  // wave 0..7
  const int wm = (wave >> 2) * (BM / 2), wn = (wave & 3) * (BN / 4);

  __shared__ __align__(16) ushort_t Asp[2][BM * 64];
  __shared__ __align__(16) ushort_t Bsp[2][BN * 64];

  const int sr = tid >> 3;                      // 0..63
  const int sc8 = (tid & 7) * 8;                // LDS chunk (lane-linear dest)
  const int sgx = ((tid & 7) ^ (sr & 7)) * 8;   // pre-swizzled global chunk

  auto stage = [&](int t, int buf) {
    const int kb = t * 64;
#pragma unroll
    for (int j = 0; j < BM / 64; ++j) {
      const int row = j * 64 + sr;
      __builtin_amdgcn_global_load_lds(
          (const __attribute__((address_space(1))) unsigned int*)
              (A + (size_t)(mb + row) * K + kb + sgx),
          (__attribute__((address_space(3))) unsigned int*)
              (&Asp[buf][row * 64 + sc8]), 16, 0, 0);
    }
#pragma unroll
    for (int j = 0; j < BN / 64; ++j) {
      const int row = j * 64 + sr;
      __builtin_amdgcn_global_load_lds(
          (const __attribute__((address_space(1))) unsigned int*)
              (Bt + (size_t)(nb + row) * K + kb + sgx),
          (__attribute__((address_space(3))) unsigned int*)
              (&Bsp[buf][row * 64 + sc8]), 16, 0, 0);
    }
  };

  stage(0, 0);
  stage(1, 1);
  wait_vmcnt<LPT>();
  __builtin_amdgcn_s_barrier();
  __builtin_amdgcn_sched_barrier(0);

  const int lc = lane & 15, kq = lane >> 4, swz = lc & 7;
  floatx4 acc[MI][NJ] = {};

#pragma unroll 1
  for (int t = 0; t < NT; ++t) {
    const int cur = t & 1;
    short8 af[MI][2], bfr[NJ][2];
#pragma unroll
    for (int ks = 0; ks < 2; ++ks) {
#pragma unroll
      for (int i = 0; i < MI; ++i)
        af[i][ks] = *(const short8*)(&Asp[cur][(wm + i * 16 + lc) * 64 +
                                               ((ks * 4 + kq) ^ swz) * 8]);
#pragma unroll
      for (int j = 0; j < NJ; ++j)
        bfr[j][ks] = *(const short8*)(&Bsp[cur][(wn + j * 16 + lc) * 64 +
                                                ((ks * 4 + kq) ^ swz) * 8]);
    }
    __builtin_amdgcn_s_setprio(1);
#pragma unroll
    for (int i = 0; i < MI; ++i)
#pragma unroll
      for (int j = 0; j < NJ; ++j)
        acc[i][j] = __builtin_amdgcn_mfma_f32_16x16x32_bf16(
            af[i][0], bfr[j][0], acc[i][j], 0, 0, 0);
    __builtin_amdgcn_s_setprio(0);
    asm volatile("s_waitcnt lgkmcnt(0)" ::: "memory");
    __builtin_amdgcn_sched_barrier(0);
    __builtin_amdgcn_s_barrier();  // #1: all waves' frag reads complete
    __builtin_amdgcn_sched_barrier(0);
    if (t + 2 < NT) stage(t + 2, cur);  // overwrite just-freed buffer
    __builtin_amdgcn_sched_barrier(0);
    if (t + 2 < NT)
      wait_vmcnt<LPT>();
    else if (t + 1 < NT)
      wait_vmcnt<0>();
    if (t + 1 < NT) {
      __builtin_amdgcn_s_barrier();  // #2: tile t+1 resident on every wave
      __builtin_amdgcn_sched_barrier(0);
    }
    __builtin_amdgcn_s_setprio(1);
#pragma unroll
    for (int i = 0; i < MI; ++i)
#pragma unroll
      for (int j = 0; j < NJ; ++j)
        acc[i][j] = __builtin_amdgcn_mfma_f32_16x16x32_bf16(
            af[i][1], bfr[j][1], acc[i][j], 0, 0, 0);
    __builtin_amdgcn_s_setprio(0);
  }

  const int lcol = lane & 15, lr4 = (lane >> 4) * 4;
#pragma unroll
  for (int i = 0; i < MI; ++i)
#pragma unroll
    for (int r = 0; r < 4; ++r) {
      const int m = mb + wm + i * 16 + lr4 + r;
#pragma unroll
      for (int j = 0; j < NJ; ++j) {
        const int col = nb + wn + j * 16 + lcol;
        float vv = acc[i][j][r];
        if (GELU) vv = gelu_f(vv);
        if (RESID) vv += resid[(size_t)m * N + col];
        if (OUT_BF16)
          ((ushort_t*)Cout)[(size_t)m * N + col] = f2bf(vv);
        else
          ((float*)Cout)[(size_t)m * N + col] = vv;
      }
    }
}

extern "C" void kernel_launch(void* const* d_in, const int* in_sizes, int n_in,
                              void* d_out, int out_size, void* d_ws, size_t ws_size,
                              hipStream_t stream) {
  (void)in_sizes; (void)n_in; (void)out_size; (void)ws_size;
  const float* x     = (const float*)d_in[0];
  const float* ln1_g = (const float*)d_in[1];
  const float* ln1_b = (const float*)d_in[2];
  const float* Wq    = (const float*)d_in[3];
  const float* bq    = (const float*)d_in[4];
  const float* Wk    = (const float*)d_in[5];
  const float* bk    = (const float*)d_in[6];
  const float* Wv    = (const float*)d_in[7];
  const float* bv    = (const float*)d_in[8];
  const float* ln2_g = (const float*)d_in[9];
  const float* ln2_b = (const float*)d_in[10];
  const float* W1    = (const float*)d_in[11];
  const float* W2    = (const float*)d_in[12];
  float* out = (float*)d_out;

  const size_t n = (size_t)B_ * S_ * D_;  // 6,291,456
  ushort_t* u = (ushort_t*)d_ws;
  ushort_t* xbf  = u;                 // LN1 out bf16
  ushort_t* qb   = xbf + n;           // [96][1024][64]
  ushort_t* kb   = qb + n;
  ushort_t* vt   = kb + n;            // [96][64][1024]  (written by qkv)
  ushort_t* xbf2 = vt + n;            // LN2 out bf16
  ushort_t* act  = xbf2 + n;          // 8192 x 3072
  ushort_t* Wt1  = act + (size_t)8192 * 3072;
  ushort_t* Wt2  = Wt1 + (size_t)3072 * 768;
  ushort_t* Wqt  = Wt2 + (size_t)768 * 3072;
  ushort_t* Wkt  = Wqt + H_ * 4096;
  ushort_t* Wvt  = Wkt + H_ * 4096;
  float* out1 = (float*)(Wvt + H_ * 4096);  // x + attn (fp32), n floats

  // weight prep + LN1 fused in ONE launch (independent work, overlapped)
  prep_ln<<<dim3(6692), dim3(256), 0, stream>>>(
      W1, Wt1, W2, Wt2, Wq, Wk, Wv, Wqt, Wkt, Wvt, x, ln1_g, ln1_b, xbf);
  qkv_mfma<<<dim3(64, 12), dim3(256), 0, stream>>>(xbf, Wqt, Wkt, Wvt,
                                                   bq, bk, bv, qb, kb, vt);
  attn_mfma<<<dim3(96, 8), dim3(512), 0, stream>>>(qb, kb, vt, x, out1);
  ln_bf16<<<dim3(2048), dim3(256), 0, stream>>>(out1, ln2_g, ln2_b, xbf2);
  // FFN GEMM1: 8192x3072x768, GELU, bf16 out (128x128, XCD rectangle map)
  gemm_pipe<128, 128, 3072, 768, true, false, true, 2>
      <<<dim3(1536), dim3(512), 0, stream>>>(xbf2, Wt1, nullptr, act);
  // FFN GEMM2: 8192x768x3072, +resid, fp32 out (64x128, 8 waves, XCD map 1)
  gemm_pipe<64, 128, 768, 3072, false, true, false, 1>
      <<<dim3(768), dim3(512), 0, stream>>>(act, Wt2, out1, out);
}